// Round 7
// baseline (238.210 us; speedup 1.0000x reference)
//
#include <hip/hip_runtime.h>
#include <math.h>

#define BB 8
#define TT 96
#define SS 192
#define DIN 512
#define DM 512
#define SCALE 2.885390082f   // 2/ln2
#define NBLK 256
#define MAGIC 0x1357BEEFu

typedef short short8 __attribute__((ext_vector_type(8)));
typedef float f32x4 __attribute__((ext_vector_type(4)));

__device__ __forceinline__ unsigned short f2bf(float f) {   // RNE
    unsigned int u = __float_as_uint(f);
    unsigned int r = u + 0x7FFFu + ((u >> 16) & 1u);
    return (unsigned short)(r >> 16);
}
__device__ __forceinline__ float bf2f(unsigned short h) {
    return __uint_as_float(((unsigned int)h) << 16);
}
__device__ __forceinline__ short8 pack_rne8(float4 a, float4 b) {
    short8 o;
    o[0] = (short)f2bf(a.x); o[1] = (short)f2bf(a.y);
    o[2] = (short)f2bf(a.z); o[3] = (short)f2bf(a.w);
    o[4] = (short)f2bf(b.x); o[5] = (short)f2bf(b.y);
    o[6] = (short)f2bf(b.z); o[7] = (short)f2bf(b.w);
    return o;
}

// sense-reversing grid barrier; bar[0]=count, bar[2]=generation (device scope)
__device__ __forceinline__ void grid_barrier(unsigned* bar) {
    __syncthreads();
    if (threadIdx.x == 0) {
        unsigned gen = __hip_atomic_load(&bar[2], __ATOMIC_RELAXED, __HIP_MEMORY_SCOPE_AGENT);
        unsigned arrived = __hip_atomic_fetch_add(&bar[0], 1u, __ATOMIC_ACQ_REL,
                                                  __HIP_MEMORY_SCOPE_AGENT) + 1u;
        if (arrived == NBLK) {
            __hip_atomic_store(&bar[0], 0u, __ATOMIC_RELAXED, __HIP_MEMORY_SCOPE_AGENT);
            __hip_atomic_store(&bar[2], gen + 1u, __ATOMIC_RELEASE, __HIP_MEMORY_SCOPE_AGENT);
        } else {
            while (__hip_atomic_load(&bar[2], __ATOMIC_ACQUIRE, __HIP_MEMORY_SCOPE_AGENT) == gen)
                __builtin_amdgcn_s_sleep(1);
        }
    }
    __syncthreads();
}

// 32x32 MFMA tile, bf16 in, K=512, depth-2 register pipeline, scaled bf16 out
__device__ __forceinline__ void mfma_tile32(
    const unsigned short* __restrict__ A, int lda,
    const unsigned short* __restrict__ W, const float* __restrict__ bias,
    unsigned short* __restrict__ out, int m0, int n0, int lane)
{
    const int mrow = lane & 15, quad = lane >> 4;
    const unsigned short* ap0 = A + (size_t)(m0 + mrow) * lda + quad * 8;
    const unsigned short* ap1 = ap0 + 16 * (size_t)lda;
    const unsigned short* bp0 = W + (size_t)(n0 + mrow) * DM + quad * 8;
    const unsigned short* bp1 = bp0 + 16 * DM;

    f32x4 c00 = {0,0,0,0}, c01 = {0,0,0,0}, c10 = {0,0,0,0}, c11 = {0,0,0,0};
    short8 a0b[2], a1b[2], b0b[2], b1b[2];
    auto ld = [&](int sl, int ks) {
        a0b[sl] = *(const short8*)(ap0 + ks * 32);
        a1b[sl] = *(const short8*)(ap1 + ks * 32);
        b0b[sl] = *(const short8*)(bp0 + ks * 32);
        b1b[sl] = *(const short8*)(bp1 + ks * 32);
    };
    ld(0, 0); ld(1, 1);
    #pragma unroll
    for (int ks = 0; ks < 16; ++ks) {
        const int sl = ks & 1;
        short8 a0 = a0b[sl], a1 = a1b[sl], b0 = b0b[sl], b1 = b1b[sl];
        if (ks + 2 < 16) ld(sl, ks + 2);
        c00 = __builtin_amdgcn_mfma_f32_16x16x32_bf16(a0, b0, c00, 0, 0, 0);
        c01 = __builtin_amdgcn_mfma_f32_16x16x32_bf16(a0, b1, c01, 0, 0, 0);
        c10 = __builtin_amdgcn_mfma_f32_16x16x32_bf16(a1, b0, c10, 0, 0, 0);
        c11 = __builtin_amdgcn_mfma_f32_16x16x32_bf16(a1, b1, c11, 0, 0, 0);
    }
    f32x4 accs[2][2] = {{c00, c01}, {c10, c11}};
    #pragma unroll
    for (int mi = 0; mi < 2; ++mi)
        #pragma unroll
        for (int ni = 0; ni < 2; ++ni) {
            int col = n0 + ni * 16 + mrow;
            float bv = bias ? bias[col] : 0.0f;
            #pragma unroll
            for (int rg = 0; rg < 4; ++rg) {
                int row = m0 + mi * 16 + quad * 4 + rg;  // C/D: col=lane&15, row=quad*4+rg
                out[(size_t)row * DM + col] = f2bf((accs[mi][ni][rg] + bv) * SCALE);
            }
        }
}

__global__ __launch_bounds__(256, 1) void fused_all(
    const float* __restrict__ inputs, const float* __restrict__ mems,
    const int* __restrict__ masks, const float* __restrict__ Wq,
    const float* __restrict__ Wc, const float* __restrict__ bc,
    const float* __restrict__ v, const float* __restrict__ Wout,
    const float* __restrict__ bout,
    unsigned* __restrict__ bar,
    unsigned short* __restrict__ mems_bf, unsigned short* __restrict__ Wq_bf,
    unsigned short* __restrict__ Wc_bf, unsigned short* __restrict__ Wout_bf,
    unsigned short* __restrict__ wq_s, unsigned short* __restrict__ uh_s,
    unsigned short* __restrict__ cat_bf,   // [768][1024]: c | inputs_bf
    float* __restrict__ attn_h, float* __restrict__ align_out)
{
    const int tid = threadIdx.x;
    const int lane = tid & 63, w = tid >> 6;
    const int gid = blockIdx.x * 4 + w;   // global wave id [0,1024)

    // ---- barrier init handshake (ws is poisoned 0xAA each call) ----
    if (blockIdx.x == 0 && tid == 0) {
        __hip_atomic_store(&bar[0], 0u, __ATOMIC_RELAXED, __HIP_MEMORY_SCOPE_AGENT);
        __hip_atomic_store(&bar[2], 0u, __ATOMIC_RELAXED, __HIP_MEMORY_SCOPE_AGENT);
        __hip_atomic_store(&bar[1], MAGIC, __ATOMIC_RELEASE, __HIP_MEMORY_SCOPE_AGENT);
    }
    if (tid == 0) {
        while (__hip_atomic_load(&bar[1], __ATOMIC_ACQUIRE, __HIP_MEMORY_SCOPE_AGENT) != MAGIC)
            __builtin_amdgcn_s_sleep(1);
    }
    __syncthreads();

    // ---- phase 0: fp32 -> bf16 conversions (grid-stride over vec8 chunks) ----
    // vec8 segments: mems 98304 | Wq 32768 | Wc 32768 | Wout 65536 | inputs 49152
    {
        const int gtid = blockIdx.x * 256 + tid;
        for (int i = gtid; i < 278528; i += NBLK * 256) {
            const float* s; unsigned short* d; int idx; int remap = 0;
            if (i < 98304)       { s = mems;   d = mems_bf; idx = i * 8; }
            else if (i < 131072) { s = Wq;     d = Wq_bf;   idx = (i - 98304) * 8; }
            else if (i < 163840) { s = Wc;     d = Wc_bf;   idx = (i - 131072) * 8; }
            else if (i < 229376) { s = Wout;   d = Wout_bf; idx = (i - 163840) * 8; }
            else                 { s = inputs; d = cat_bf;  idx = (i - 229376) * 8; remap = 1; }
            float4 a = *(const float4*)(s + idx);
            float4 b = *(const float4*)(s + idx + 4);
            int dst = remap ? ((idx >> 9) * 1024 + 512 + (idx & 511)) : idx;
            *(short8*)(d + dst) = pack_rne8(a, b);
        }
    }
    grid_barrier(bar);

    // ---- phase 1: proj GEMMs (wq: 384 tiles, uh: 768 tiles; 32x32 each) ----
    {
        auto do_tile = [&](int t) {
            if (t < 384) {
                mfma_tile32(cat_bf + 512, 1024, Wq_bf, nullptr, wq_s,
                            (t % 24) * 32, (t / 24) * 32, lane);
            } else {
                int g = t - 384;
                mfma_tile32(mems_bf, DM, Wc_bf, bc, uh_s,
                            (g % 48) * 32, (g / 48) * 32, lane);
            }
        };
        do_tile(gid);
        if (gid < 128) do_tile(1024 + gid);
    }
    grid_barrier(bar);

    // ---- phase 2: scores + softmax + context, 3 rows per block ----
    {
        __shared__ float s_al[3][SS];
        __shared__ float s_part[4][3][DM];
        __shared__ float s_inv[3];
        const int r0 = blockIdx.x * 3, b = r0 / TT;
        const int len = masks[b];
        const int mgrp = lane & 15, ssub = lane >> 4;

        float qv[3][4][8], wv[4][8], vsum = 0.f;
        #pragma unroll
        for (int inner = 0; inner < 4; ++inner) {
            float4 va = *(const float4*)(v + inner * 128 + mgrp * 8);
            float4 vb = *(const float4*)(v + inner * 128 + mgrp * 8 + 4);
            float vt[8] = {va.x, va.y, va.z, va.w, vb.x, vb.y, vb.z, vb.w};
            #pragma unroll
            for (int j = 0; j < 8; ++j) { vsum += vt[j]; wv[inner][j] = -2.f * vt[j]; }
            #pragma unroll
            for (int r = 0; r < 3; ++r) {
                short8 q8 = *(const short8*)(wq_s + (size_t)(r0 + r) * DM + inner * 128 + mgrp * 8);
                #pragma unroll
                for (int j = 0; j < 8; ++j) qv[r][inner][j] = bf2f((unsigned short)q8[j]);
            }
        }

        for (int it = 0; it < 12; ++it) {
            const int s = w * 48 + it * 4 + ssub;
            const unsigned short* up = uh_s + ((size_t)b * SS + s) * DM + mgrp * 8;
            short8 u[4];
            #pragma unroll
            for (int inner = 0; inner < 4; ++inner)
                u[inner] = *(const short8*)(up + inner * 128);
            float acc[3] = {vsum, vsum, vsum};
            #pragma unroll
            for (int inner = 0; inner < 4; ++inner)
                #pragma unroll
                for (int j = 0; j < 8; ++j) {
                    float uf = bf2f((unsigned short)u[inner][j]);
                    #pragma unroll
                    for (int r = 0; r < 3; ++r) {
                        float e = __builtin_amdgcn_exp2f(qv[r][inner][j] + uf);
                        float rc = __builtin_amdgcn_rcpf(e + 1.f);
                        acc[r] = fmaf(wv[inner][j], rc, acc[r]);
                    }
                }
            #pragma unroll
            for (int r = 0; r < 3; ++r) {
                float a = acc[r];
                a += __shfl_xor(a, 1); a += __shfl_xor(a, 2);
                a += __shfl_xor(a, 4); a += __shfl_xor(a, 8);
                if (mgrp == 0) s_al[r][s] = (s < len) ? a : -INFINITY;
            }
        }
        __syncthreads();

        if (w < 3) {   // wave w -> row w softmax
            float* sa = s_al[w];
            float m = fmaxf(fmaxf(sa[lane], sa[lane + 64]), sa[lane + 128]);
            #pragma unroll
            for (int off = 32; off; off >>= 1) m = fmaxf(m, __shfl_xor(m, off));
            float e0 = __builtin_amdgcn_exp2f((sa[lane]       - m) * 1.44269504f);
            float e1 = __builtin_amdgcn_exp2f((sa[lane + 64]  - m) * 1.44269504f);
            float e2 = __builtin_amdgcn_exp2f((sa[lane + 128] - m) * 1.44269504f);
            sa[lane] = e0; sa[lane + 64] = e1; sa[lane + 128] = e2;
            float sum = e0 + e1 + e2;
            #pragma unroll
            for (int off = 32; off; off >>= 1) sum += __shfl_xor(sum, off);
            if (lane == 0) s_inv[w] = 1.0f / sum;
        }
        __syncthreads();

        #pragma unroll
        for (int r = 0; r < 3; ++r)
            if (tid < SS)
                align_out[(size_t)(r0 + r) * SS + tid] = s_al[r][tid] * s_inv[r];

        // context: wave w covers s in [w*48,+48); lane owns d = lane*8..+8
        float ac[3][8] = {};
        const unsigned short* mb = mems_bf + ((size_t)b * SS + w * 48) * DM + lane * 8;
        #pragma unroll 4
        for (int i = 0; i < 48; ++i) {
            short8 mv = *(const short8*)(mb + (size_t)i * DM);
            float p0 = s_al[0][w * 48 + i], p1 = s_al[1][w * 48 + i], p2 = s_al[2][w * 48 + i];
            #pragma unroll
            for (int j = 0; j < 8; ++j) {
                float f = bf2f((unsigned short)mv[j]);
                ac[0][j] = fmaf(p0, f, ac[0][j]);
                ac[1][j] = fmaf(p1, f, ac[1][j]);
                ac[2][j] = fmaf(p2, f, ac[2][j]);
            }
        }
        #pragma unroll
        for (int r = 0; r < 3; ++r)
            #pragma unroll
            for (int j = 0; j < 8; ++j) s_part[w][r][lane * 8 + j] = ac[r][j];
        __syncthreads();

        const int d = tid * 2;
        #pragma unroll
        for (int r = 0; r < 3; ++r) {
            float x0 = s_part[0][r][d]     + s_part[1][r][d]     + s_part[2][r][d]     + s_part[3][r][d];
            float x1 = s_part[0][r][d + 1] + s_part[1][r][d + 1] + s_part[2][r][d + 1] + s_part[3][r][d + 1];
            float iv = s_inv[r];
            unsigned int pack = ((unsigned int)f2bf(x1 * iv) << 16) | (unsigned int)f2bf(x0 * iv);
            *(unsigned int*)(cat_bf + (size_t)(r0 + r) * 1024 + d) = pack;
        }
    }
    grid_barrier(bar);

    // ---- phase 3: attn_h = cat([c, inputs]) @ Wout^T + bout (768 16x32 tiles) ----
    if (gid < 768) {
        const int m0 = (gid % 48) * 16, n0 = (gid / 48) * 32;
        const int mrow = lane & 15, quad = lane >> 4;
        const unsigned short* ap = cat_bf + (size_t)(m0 + mrow) * 1024 + quad * 8;
        const unsigned short* bp0 = Wout_bf + (size_t)(n0 + mrow) * 1024 + quad * 8;
        const unsigned short* bp1 = bp0 + 16 * 1024;

        f32x4 c0 = {0,0,0,0}, c1 = {0,0,0,0};
        short8 ab[2], b0b[2], b1b[2];
        auto ld = [&](int sl, int ks) {
            ab[sl]  = *(const short8*)(ap  + ks * 32);
            b0b[sl] = *(const short8*)(bp0 + ks * 32);
            b1b[sl] = *(const short8*)(bp1 + ks * 32);
        };
        ld(0, 0); ld(1, 1);
        #pragma unroll
        for (int ks = 0; ks < 32; ++ks) {
            const int sl = ks & 1;
            short8 a = ab[sl], b0 = b0b[sl], b1 = b1b[sl];
            if (ks + 2 < 32) ld(sl, ks + 2);
            c0 = __builtin_amdgcn_mfma_f32_16x16x32_bf16(a, b0, c0, 0, 0, 0);
            c1 = __builtin_amdgcn_mfma_f32_16x16x32_bf16(a, b1, c1, 0, 0, 0);
        }
        f32x4 accs[2] = {c0, c1};
        #pragma unroll
        for (int ni = 0; ni < 2; ++ni) {
            int col = n0 + ni * 16 + mrow;
            float bv = bout[col];
            #pragma unroll
            for (int rg = 0; rg < 4; ++rg) {
                int row = m0 + quad * 4 + rg;
                attn_h[(size_t)row * DIN + col] = accs[ni][rg] + bv;
            }
        }
    }
}

extern "C" void kernel_launch(void* const* d_in, const int* in_sizes, int n_in,
                              void* d_out, int out_size, void* d_ws, size_t ws_size,
                              hipStream_t stream) {
    (void)in_sizes; (void)n_in; (void)out_size; (void)ws_size;
    const float* inputs = (const float*)d_in[0];
    const float* mems   = (const float*)d_in[1];
    const int*   masks  = (const int*)  d_in[2];
    const float* Wq     = (const float*)d_in[3];
    const float* Wc     = (const float*)d_in[4];
    const float* bc     = (const float*)d_in[5];
    const float* v      = (const float*)d_in[6];
    const float* Wout   = (const float*)d_in[7];
    const float* bout   = (const float*)d_in[8];

    unsigned* bar = (unsigned*)d_ws;                       // 64 uints (256 B)
    unsigned short* p = (unsigned short*)((char*)d_ws + 256);
    unsigned short* mems_bf = p;  p += 786432;   // [1536][512]
    unsigned short* Wq_bf   = p;  p += 262144;   // [512][512]
    unsigned short* Wc_bf   = p;  p += 262144;   // [512][512]
    unsigned short* Wout_bf = p;  p += 524288;   // [512][1024]
    unsigned short* wq_s    = p;  p += 393216;   // [768][512]  scaled 2/ln2
    unsigned short* uh_s    = p;  p += 786432;   // [1536][512] scaled 2/ln2
    unsigned short* cat_bf  = p;  p += 786432;   // [768][1024] c | inputs

    float* attn_h    = (float*)d_out;                    // [768][512]
    float* align_out = attn_h + (size_t)BB * TT * DIN;   // [768][192]

    fused_all<<<NBLK, 256, 0, stream>>>(inputs, mems, masks, Wq, Wc, bc, v, Wout, bout,
                                        bar, mems_bf, Wq_bf, Wc_bf, Wout_bf,
                                        wq_s, uh_s, cat_bf, attn_h, align_out);
}